// Round 1
// baseline (444.240 us; speedup 1.0000x reference)
//
#include <hip/hip_runtime.h>

#define NZ 32
#define NY 1024
#define NX 1024

__device__ __forceinline__ float rcpf(float x) { return __builtin_amdgcn_rcpf(x); }

// Classic Jiang-Shu WENO5 reconstruction at the i+1/2 face (left-biased).
__device__ __forceinline__ float weno5(float qm2, float qm1, float q0, float qp1, float qp2) {
    const float c1312 = 13.0f / 12.0f;
    float t0 = qm2 - 2.0f * qm1 + q0;
    float u0 = qm2 - 4.0f * qm1 + 3.0f * q0;
    float b0 = c1312 * t0 * t0 + 0.25f * u0 * u0;
    float t1 = qm1 - 2.0f * q0 + qp1;
    float u1 = qm1 - qp1;
    float b1 = c1312 * t1 * t1 + 0.25f * u1 * u1;
    float t2 = q0 - 2.0f * qp1 + qp2;
    float u2 = 3.0f * q0 - 4.0f * qp1 + qp2;
    float b2 = c1312 * t2 * t2 + 0.25f * u2 * u2;
    float e0 = 1e-6f + b0;
    float e1 = 1e-6f + b1;
    float e2 = 1e-6f + b2;
    // 1-ulp hardware reciprocal is far inside the 5.7e-4 tolerance.
    float a0 = 0.1f * rcpf(e0 * e0);
    float a1 = 0.6f * rcpf(e1 * e1);
    float a2 = 0.3f * rcpf(e2 * e2);
    const float c16 = 1.0f / 6.0f;
    float p0 = (2.0f * qm2 - 7.0f * qm1 + 11.0f * q0) * c16;
    float p1 = (-qm1 + 5.0f * q0 + 2.0f * qp1) * c16;
    float p2 = (2.0f * q0 + 5.0f * qp1 - qp2) * c16;
    return (a0 * p0 + a1 * p1 + a2 * p2) * rcpf(a0 + a1 + a2);
}

// Upwinded flux at face i+1/2 given the 6-wide stencil q[i-2..i+3] and vel at cell i.
__device__ __forceinline__ float upwind_flux(float vel, float qm2, float qm1, float q0,
                                             float qp1, float qp2, float qp3) {
    bool up = vel >= 0.0f;
    float s0 = up ? qm2 : qp3;
    float s1 = up ? qm1 : qp2;
    float s2 = up ? q0  : qp1;
    float s3 = up ? qp1 : q0;
    float s4 = up ? qp2 : qm1;
    return vel * weno5(s0, s1, s2, s3, s4);
}

__global__ __launch_bounds__(256) void adv_kernel(const float* __restrict__ h,
                                                  const float* __restrict__ u,
                                                  const float* __restrict__ v,
                                                  float* __restrict__ out) {
    int x = blockIdx.x * blockDim.x + threadIdx.x;
    int y = blockIdx.y;
    int z = blockIdx.z;
    size_t base = ((size_t)z * NY + y) * NX;
    size_t idx = base + x;

    bool interior = (z >= 1) && (z <= NZ - 2) && (y >= 2) && (y <= NY - 3) &&
                    (x >= 2) && (x <= NX - 3);
    if (!interior) {
        out[idx] = 0.0f;   // boundary is exactly zero in the reference
        return;
    }

    // ---- x-direction: h[x-3 .. x+3] (clamped = edge padding) ----
    const float* row = h + base;
    float hx[7];
#pragma unroll
    for (int k = 0; k < 7; ++k) {
        int xx = x - 3 + k;
        xx = xx < 0 ? 0 : (xx > NX - 1 ? NX - 1 : xx);
        hx[k] = row[xx];
    }
    float fe_hi = upwind_flux(u[idx],     hx[1], hx[2], hx[3], hx[4], hx[5], hx[6]); // face at x
    float fe_lo = upwind_flux(u[idx - 1], hx[0], hx[1], hx[2], hx[3], hx[4], hx[5]); // face at x-1

    // ---- y-direction: h[y-3 .. y+3][x] (clamped) ----
    float hy[7];
#pragma unroll
    for (int k = 0; k < 7; ++k) {
        int yy = y - 3 + k;
        yy = yy < 0 ? 0 : (yy > NY - 1 ? NY - 1 : yy);
        hy[k] = h[((size_t)z * NY + yy) * NX + x];
    }
    float fn_hi = upwind_flux(v[idx],      hy[1], hy[2], hy[3], hy[4], hy[5], hy[6]); // face at y
    float fn_lo = upwind_flux(v[idx - NX], hy[0], hy[1], hy[2], hy[3], hy[4], hy[5]); // face at y-1

    const float inv_dx = 1.0f / 1000.0f;
    const float inv_dy = 1.0f / 1000.0f;
    out[idx] = -((fe_hi - fe_lo) * inv_dx + (fn_hi - fn_lo) * inv_dy);
}

extern "C" void kernel_launch(void* const* d_in, const int* in_sizes, int n_in,
                              void* d_out, int out_size, void* d_ws, size_t ws_size,
                              hipStream_t stream) {
    const float* h = (const float*)d_in[0];
    const float* u = (const float*)d_in[1];
    const float* v = (const float*)d_in[2];
    float* out = (float*)d_out;

    dim3 block(256, 1, 1);
    dim3 grid(NX / 256, NY, NZ);
    adv_kernel<<<grid, block, 0, stream>>>(h, u, v, out);
}